// Round 17
// baseline (650.752 us; speedup 1.0000x reference)
//
#include <hip/hip_runtime.h>
#include <math.h>

// Problem constants: B=4, T=8, C=d=256, H=W=48, L=2, nh=8, dk=32
#define SEQ   9216          // B*H*W
#define TOK   73728         // SEQ*T

typedef short bf16x8 __attribute__((ext_vector_type(8)));
typedef short bf16x4 __attribute__((ext_vector_type(4)));
typedef float f32x4  __attribute__((ext_vector_type(4)));

#define GLD_LDS16(gsrc, ldst)                                                      \
    __builtin_amdgcn_global_load_lds(                                              \
        (const __attribute__((address_space(1))) unsigned int*)(gsrc),             \
        (__attribute__((address_space(3))) unsigned int*)(ldst), 16, 0, 0)

__device__ __forceinline__ unsigned short f2bf(float f) {
    unsigned u = __builtin_bit_cast(unsigned, f);
    unsigned r = (u + 0x7fffu + ((u >> 16) & 1u)) >> 16;
    return (unsigned short)r;
}
__device__ __forceinline__ float bf2f(unsigned short h) {
    return __builtin_bit_cast(float, (unsigned)h << 16);
}

// ---------------------------------------------------------------------------
// One-shot setup: weight bf16 conversion (blocks 0..1535), pe table
// (1536..1543), packed qkv bias (1544..1549).
__global__ void setup_all(const float* __restrict__ Wq, const float* __restrict__ Wk,
                          const float* __restrict__ Wv, const float* __restrict__ Wo,
                          const float* __restrict__ W1, const float* __restrict__ W2,
                          const float* __restrict__ bq, const float* __restrict__ bk,
                          const float* __restrict__ bv,
                          unsigned short* __restrict__ wB, float* __restrict__ pe,
                          float* __restrict__ bqkv) {
    int b = blockIdx.x, tid = threadIdx.x;
    if (b < 1536) {
        int i4 = b * 256 + tid;              // vec4 index over 2x786432 elems
        int e = i4 * 4;
        int l = (e >= 786432) ? 1 : 0;
        int r = e - l * 786432;
        const float* src;
        int off;
        if (r < 262144) {                    // Wq|Wk|Wv|Wo, 65536 each
            int w = r >> 16;
            off = (l << 16) + (r & 65535);
            src = (w == 0) ? Wq : (w == 1) ? Wk : (w == 2) ? Wv : Wo;
        } else if (r < 524288) {
            off = l * 262144 + (r - 262144);
            src = W1;
        } else {
            off = l * 262144 + (r - 524288);
            src = W2;
        }
        float4 v = *(const float4*)(src + off);
        unsigned short* o = wB + (size_t)l * 786432 + r;
        o[0] = f2bf(v.x); o[1] = f2bf(v.y); o[2] = f2bf(v.z); o[3] = f2bf(v.w);
    } else if (b < 1544) {
        int idx = (b - 1536) * 256 + tid;    // 0..2047
        int t = idx >> 8, c = idx & 255;
        int i2 = c & ~1;
        float div = __expf((float)i2 * (-logf(10000.f) / 256.f));
        float ang = (float)t * div;
        pe[idx] = (c & 1) ? cosf(ang) : sinf(ang);
    } else {
        int j = (b - 1544) * 256 + tid;      // 0..1535
        int l = j / 768, i = j - l * 768;
        float v = (i < 256) ? bq[l * 256 + i] : (i < 512) ? bk[l * 256 + i - 256]
                                                          : bv[l * 256 + i - 512];
        bqkv[j] = v;
    }
}

// ---------------------------------------------------------------------------
// x (B,T,C,H,W) -> hb (n, t, c) bf16, with += pe[t,c].
__global__ __launch_bounds__(256) void transpose_in(const float* __restrict__ x,
                                                    const float* __restrict__ pe,
                                                    unsigned short* __restrict__ hb) {
    int bty = blockIdx.x;
    int y = bty % 48; int bt = bty / 48; int t = bt & 7; int b = bt >> 3;
    int c0 = blockIdx.y * 32, w0 = blockIdx.z * 32;
    __shared__ float tile[32][33];
    int tid = threadIdx.x;
    const float* xp = x + ((size_t)(b * 8 + t) * 256) * 2304 + (size_t)y * 48;
    int wl = tid & 31, cl8 = tid >> 5;
#pragma unroll
    for (int it = 0; it < 4; ++it) {
        int c = c0 + it * 8 + cl8;
        int w = w0 + wl;
        if (w < 48) tile[it * 8 + cl8][wl] = xp[(size_t)c * 2304 + w] + pe[t * 256 + c];
    }
    __syncthreads();
    int cl = tid & 31, wl8 = tid >> 5;
#pragma unroll
    for (int it = 0; it < 4; ++it) {
        int w = w0 + it * 8 + wl8;
        int c = c0 + cl;
        if (w < 48) {
            size_t n = (size_t)(b * 48 + y) * 48 + w;
            hb[(n * 8 + t) * 256 + c] = f2bf(tile[cl][it * 8 + wl8]);
        }
    }
}

// out (B,C,H,W) fp32 = hb[n, T-1, c]
__global__ __launch_bounds__(256) void transpose_out(const unsigned short* __restrict__ hb,
                                                     float* __restrict__ out) {
    int by = blockIdx.x; int y = by % 48, b = by / 48;
    int c0 = blockIdx.y * 32, w0 = blockIdx.z * 32;
    __shared__ float tile[32][33];
    int tid = threadIdx.x;
    int cl = tid & 31, wl8 = tid >> 5;
#pragma unroll
    for (int it = 0; it < 4; ++it) {
        int w = w0 + it * 8 + wl8;
        if (w < 48) {
            size_t n = (size_t)(b * 48 + y) * 48 + w;
            tile[it * 8 + wl8][cl] = bf2f(hb[n * 2048 + 1792 + c0 + cl]);
        }
    }
    __syncthreads();
    int wl = tid & 31, cl8 = tid >> 5;
#pragma unroll
    for (int it = 0; it < 4; ++it) {
        int c = c0 + it * 8 + cl8;
        int w = w0 + wl;
        if (w < 48)
            out[((size_t)(b * 256 + c) * 48 + y) * 48 + w] = tile[wl][it * 8 + cl8];
    }
}

// ---------------------------------------------------------------------------
// bf16 MFMA GEMM: 128x128 tile, BK=32, 32 KB double-buffer -> 4 blocks/CU,
// counted vmcnt(4); swizzle slot ^= (row>>1)&3 both-sides; setprio; XCD
// swizzle. OPERAND-SWAP MFMA (mfma(fB,fA), R6/R7-proven): lane holds C-row
// = ...+lr and 4 CONSECUTIVE cols ...+lk*4+r -> epilogue restage is 16
// vectorized ds_write_b64 (was 64 scalar b16), bias is float4. 16B C stores.
// ACT=1: fast tanh-GELU.
template <int ACT>
__global__ __launch_bounds__(256) void mgemm(const unsigned short* __restrict__ A,
                                             const unsigned short* __restrict__ W,
                                             const float* __restrict__ bias,
                                             unsigned short* __restrict__ C,
                                             int M, int N, int K) {
    __shared__ char smem[36864];          // loop: 32 KB dbuf; epi: [128][144] bf16
    const int tid = threadIdx.x;
    int nwg = gridDim.x * gridDim.y;
    int orig = blockIdx.y * gridDim.x + blockIdx.x;
    int wg = (orig & 7) * (nwg >> 3) + (orig >> 3);
    int bx = wg % gridDim.x, by = wg / gridDim.x;
    const int m0 = by * 128, n0 = bx * 128;
    const int lane = tid & 63, wv = tid >> 6;
    const int wr = wv >> 1, wc = wv & 1;
    const int lr = lane & 15, lk = lane >> 4;

    f32x4 acc[4][4] = {};

    int so[2], srow[2], sseg[2];
#pragma unroll
    for (int it = 0; it < 2; ++it) {
        int o = it * 4096 + tid * 16;
        so[it] = o;
        srow[it] = o >> 6;
        sseg[it] = ((o >> 4) & 3) ^ ((srow[it] >> 1) & 3);
    }

    const int nt = K >> 5;
#pragma unroll
    for (int it = 0; it < 2; ++it)
        GLD_LDS16(W + (size_t)(n0 + srow[it]) * K + sseg[it] * 8, smem + 16384 + so[it]);
#pragma unroll
    for (int it = 0; it < 2; ++it)
        GLD_LDS16(A + (size_t)(m0 + srow[it]) * K + sseg[it] * 8, smem + so[it]);

    int cur = 0;
    for (int t = 0; t < nt; ++t) {
        char* Ac = smem + cur * 8192;
        char* Bc = smem + 16384 + cur * 8192;
        if (t + 1 < nt) {
            const int k1 = (t + 1) << 5;
            char* An = smem + (cur ^ 1) * 8192;
            char* Bn = smem + 16384 + (cur ^ 1) * 8192;
#pragma unroll
            for (int it = 0; it < 2; ++it)
                GLD_LDS16(W + (size_t)(n0 + srow[it]) * K + k1 + sseg[it] * 8, Bn + so[it]);
#pragma unroll
            for (int it = 0; it < 2; ++it)
                GLD_LDS16(A + (size_t)(m0 + srow[it]) * K + k1 + sseg[it] * 8, An + so[it]);
            asm volatile("s_waitcnt vmcnt(4)" ::: "memory");
        } else {
            asm volatile("s_waitcnt vmcnt(0)" ::: "memory");
        }
        __builtin_amdgcn_s_barrier();
        __builtin_amdgcn_s_setprio(1);
        {
            bf16x8 fA[4], fB[4];
#pragma unroll
            for (int f = 0; f < 4; ++f) {
                int row = wr * 64 + f * 16 + lr;
                fA[f] = *(const bf16x8*)(Ac + row * 64 + ((lk ^ ((row >> 1) & 3)) << 4));
                int col = wc * 64 + f * 16 + lr;
                fB[f] = *(const bf16x8*)(Bc + col * 64 + ((lk ^ ((col >> 1) & 3)) << 4));
            }
            // operand-swap: D fragment is C^T -> lane owns one row, 4 cols
#pragma unroll
            for (int fi = 0; fi < 4; ++fi)
#pragma unroll
                for (int fj = 0; fj < 4; ++fj)
                    acc[fi][fj] = __builtin_amdgcn_mfma_f32_16x16x32_bf16(
                        fB[fj], fA[fi], acc[fi][fj], 0, 0, 0);
        }
        __builtin_amdgcn_s_setprio(0);
        __builtin_amdgcn_s_barrier();
        cur ^= 1;
    }

    // epilogue: lane's fragment = row (wr*64+fi*16+lr), cols (wc*64+fj*16+lk*4..+3)
    unsigned short* S = (unsigned short*)smem;
#pragma unroll
    for (int fi = 0; fi < 4; ++fi) {
        int rl = wr * 64 + fi * 16 + lr;
#pragma unroll
        for (int fj = 0; fj < 4; ++fj) {
            int cl = wc * 64 + fj * 16 + lk * 4;
            float4 bv = *(const float4*)&bias[n0 + cl];
            const float* bp = &bv.x;
            bf16x4 ob;
#pragma unroll
            for (int r = 0; r < 4; ++r) {
                float v = acc[fi][fj][r] + bp[r];
                if (ACT) {
                    // tanh-GELU: x*sigmoid(2*0.79788456*(x+0.044715x^3))
                    float u = 0.7978845608f * (v + 0.044715f * v * v * v);
                    v = v / (1.0f + __expf(-2.0f * u));
                }
                ob[r] = (short)f2bf(v);
            }
            *(bf16x4*)&S[rl * 144 + cl] = ob;
        }
    }
    __syncthreads();
#pragma unroll
    for (int it = 0; it < 8; ++it) {
        int idx = it * 256 + tid;
        int row = idx >> 4, c8 = (idx & 15) * 8;
        bf16x8 v = *(const bf16x8*)&S[row * 144 + c8];
        *(bf16x8*)&C[(size_t)(m0 + row) * N + n0 + c8] = v;
    }
}

// ---------------------------------------------------------------------------
// Streaming residual + LayerNorm on the bf16 carrier:
//   z = hb + c (fp32 math);  hb = bf16( (z-mean)/sqrt(var+eps)*g + be )
__global__ __launch_bounds__(256) void resln(const unsigned short* __restrict__ c,
                                             unsigned short* __restrict__ hb,
                                             const float* __restrict__ g,
                                             const float* __restrict__ be) {
    int wv = threadIdx.x >> 6, lane = threadIdx.x & 63;
    size_t row = (size_t)blockIdx.x * 4 + wv;
    size_t off = row * 256 + lane * 4;
    bf16x4 hv = *(const bf16x4*)&hb[off];
    bf16x4 cv = *(const bf16x4*)&c[off];
    float4 z = {bf2f((unsigned short)hv[0]) + bf2f((unsigned short)cv[0]),
                bf2f((unsigned short)hv[1]) + bf2f((unsigned short)cv[1]),
                bf2f((unsigned short)hv[2]) + bf2f((unsigned short)cv[2]),
                bf2f((unsigned short)hv[3]) + bf2f((unsigned short)cv[3])};
    float s = z.x + z.y + z.z + z.w;
    float sq = z.x * z.x + z.y * z.y + z.z * z.z + z.w * z.w;
#pragma unroll
    for (int d = 1; d < 64; d <<= 1) {
        s += __shfl_xor(s, d);
        sq += __shfl_xor(sq, d);
    }
    float mean = s * (1.f / 256.f);
    float var = sq * (1.f / 256.f) - mean * mean;   // biased var
    float inv = 1.0f / sqrtf(var + 1e-5f);
    float4 gv = *(const float4*)&g[lane * 4];
    float4 bv = *(const float4*)&be[lane * 4];
    bf16x4 ob;
    ob[0] = (short)f2bf((z.x - mean) * inv * gv.x + bv.x);
    ob[1] = (short)f2bf((z.y - mean) * inv * gv.y + bv.y);
    ob[2] = (short)f2bf((z.z - mean) * inv * gv.z + bv.z);
    ob[3] = (short)f2bf((z.w - mean) * inv * gv.w + bv.w);
    *(bf16x4*)&hb[off] = ob;
}

// ---------------------------------------------------------------------------
// Causal MHSA: qkv packed bf16 [row][768] (q|k|v), ctx out bf16 [row][256].
__global__ __launch_bounds__(256) void attn_kernel(const unsigned short* __restrict__ qkv,
                                                   unsigned short* __restrict__ ctx) {
    __shared__ float Qs[8 * 260], Ks[8 * 260], Vs[8 * 260];
    int n = blockIdx.x;
    int tid = threadIdx.x;
    size_t base = (size_t)n * 6144;             // 8*768
#pragma unroll
    for (int it = 0; it < 6; ++it) {
        int i4 = it * 256 + tid;                // 0..1535
        int t = i4 / 192;
        int c4 = (i4 - t * 192) * 4;            // 0..764, mult of 4
        const unsigned short* p = qkv + base + (size_t)t * 768 + c4;
        float4 f = {bf2f(p[0]), bf2f(p[1]), bf2f(p[2]), bf2f(p[3])};
        float* dst = (c4 < 256) ? &Qs[t * 260 + c4]
                   : (c4 < 512) ? &Ks[t * 260 + (c4 - 256)]
                                : &Vs[t * 260 + (c4 - 512)];
        *(float4*)dst = f;
    }
    __syncthreads();
    int wid = tid >> 6, lane = tid & 63;
    int t = lane >> 3, s = lane & 7;
    size_t obase = (size_t)n * 2048;
    for (int hh = wid; hh < 8; hh += 4) {
        float acc = 0.f;
        int qb = t * 260 + hh * 32, kb = s * 260 + hh * 32;
#pragma unroll
        for (int jj = 0; jj < 8; ++jj) {
            float4 qv = *(const float4*)&Qs[qb + jj * 4];
            float4 kv = *(const float4*)&Ks[kb + jj * 4];
            acc += qv.x * kv.x + qv.y * kv.y + qv.z * kv.z + qv.w * kv.w;
        }
        acc *= 0.17677669529663687f;            // 1/sqrt(32)
        if (s > t) acc = -1e30f;
        float m = acc;
        m = fmaxf(m, __shfl_xor(m, 1));
        m = fmaxf(m, __shfl_xor(m, 2));
        m = fmaxf(m, __shfl_xor(m, 4));
        float e = __expf(acc - m);
        float sum = e;
        sum += __shfl_xor(sum, 1);
        sum += __shfl_xor(sum, 2);
        sum += __shfl_xor(sum, 4);
        float p = e / sum;
        float a4[4] = {0.f, 0.f, 0.f, 0.f};
#pragma unroll
        for (int s2 = 0; s2 < 8; ++s2) {
            float ps = __shfl(p, (lane & ~7) | s2);
            int vb = s2 * 260 + hh * 32 + s;
#pragma unroll
            for (int r = 0; r < 4; ++r) a4[r] += ps * Vs[vb + 8 * r];
        }
#pragma unroll
        for (int r = 0; r < 4; ++r)
            ctx[obase + t * 256 + hh * 32 + s + 8 * r] = f2bf(a4[r]);
    }
}

// ---------------------------------------------------------------------------
extern "C" void kernel_launch(void* const* d_in, const int* in_sizes, int n_in,
                              void* d_out, int out_size, void* d_ws, size_t ws_size,
                              hipStream_t stream) {
    const float* x   = (const float*)d_in[0];
    const float* Wq  = (const float*)d_in[1];
    const float* bq  = (const float*)d_in[2];
    const float* Wk  = (const float*)d_in[3];
    const float* bk  = (const float*)d_in[4];
    const float* Wv  = (const float*)d_in[5];
    const float* bv  = (const float*)d_in[6];
    const float* Wo  = (const float*)d_in[7];
    const float* bo  = (const float*)d_in[8];
    const float* g1  = (const float*)d_in[9];
    const float* be1 = (const float*)d_in[10];
    const float* W1  = (const float*)d_in[11];
    const float* b1  = (const float*)d_in[12];
    const float* W2  = (const float*)d_in[13];
    const float* b2  = (const float*)d_in[14];
    const float* g2  = (const float*)d_in[15];
    const float* be2 = (const float*)d_in[16];

    // ---- workspace layout (bytes); end = 229,662,720 < proven 264.3 MB ----
    char* base = (char*)d_ws;
    const size_t O_PE = 0;                           // 16 KB reserved
    const size_t O_W  = 16384;                       // bf16 weights: 3,145,728
    const size_t O_BQ = O_W + 3145728;               // packed qkv bias (8 KB)
    const size_t O_HB = O_BQ + 8192;                 // hb bf16: 37,748,736
    const size_t O_P1 = O_HB + (size_t)TOK * 512;    // qkv/wo-out/f1o pool
    const size_t O_CT = O_P1 + (size_t)TOK * 2048;   // ctx / f2-out

    float*          pe   = (float*)(base + O_PE);
    unsigned short* wB   = (unsigned short*)(base + O_W);
    float*          bqkv = (float*)(base + O_BQ);
    unsigned short* hb   = (unsigned short*)(base + O_HB);
    unsigned short* p1   = (unsigned short*)(base + O_P1);
    unsigned short* ctxb = (unsigned short*)(base + O_CT);

    setup_all<<<1550, 256, 0, stream>>>(Wq, Wk, Wv, Wo, W1, W2, bq, bk, bv,
                                        wB, pe, bqkv);
    transpose_in<<<dim3(1536, 8, 2), 256, 0, stream>>>(x, pe, hb);

    const int gy = TOK / 128;                        // 576
    for (int l = 0; l < 2; ++l) {
        unsigned short* wqkv = wB + (size_t)l * 786432;
        unsigned short* wo   = wqkv + 196608;
        unsigned short* w1   = wqkv + 262144;
        unsigned short* w2   = wqkv + 524288;

        // fused qkv projection (N=768) -> p1
        mgemm<0><<<dim3(6, gy), 256, 0, stream>>>(hb, wqkv, bqkv + l * 768, p1, TOK, 768, 256);
        attn_kernel<<<SEQ, 256, 0, stream>>>(p1, ctxb);
        // Wo projection: reads ctx, writes wo-out into p1 (qkv dead)
        mgemm<0><<<dim3(2, gy), 256, 0, stream>>>(ctxb, wo, bo + l * 256, p1, TOK, 256, 256);
        resln<<<TOK / 4, 256, 0, stream>>>(p1, hb, g1 + l * 256, be1 + l * 256);
        // FFN up + GELU -> p1 (wo-out dead)
        mgemm<1><<<dim3(8, gy), 256, 0, stream>>>(hb, w1, b1 + l * 1024, p1, TOK, 1024, 256);
        // FFN down -> ctx slot (dead since wo)
        mgemm<0><<<dim3(2, gy), 256, 0, stream>>>(p1, w2, b2 + l * 256, ctxb, TOK, 256, 1024);
        resln<<<TOK / 4, 256, 0, stream>>>(ctxb, hb, g2 + l * 256, be2 + l * 256);
    }

    transpose_out<<<dim3(192, 8, 2), 256, 0, stream>>>(hb, (float*)d_out);
}

// Round 18
// 576.313 us; speedup vs baseline: 1.1292x; 1.1292x over previous
//
#include <hip/hip_runtime.h>
#include <math.h>

// Problem constants: B=4, T=8, C=d=256, H=W=48, L=2, nh=8, dk=32
#define SEQ   9216          // B*H*W
#define TOK   73728         // SEQ*T

typedef short bf16x8 __attribute__((ext_vector_type(8)));
typedef short bf16x4 __attribute__((ext_vector_type(4)));
typedef float f32x4  __attribute__((ext_vector_type(4)));

#define GLD_LDS16(gsrc, ldst)                                                      \
    __builtin_amdgcn_global_load_lds(                                              \
        (const __attribute__((address_space(1))) unsigned int*)(gsrc),             \
        (__attribute__((address_space(3))) unsigned int*)(ldst), 16, 0, 0)

__device__ __forceinline__ unsigned short f2bf(float f) {
    unsigned u = __builtin_bit_cast(unsigned, f);
    unsigned r = (u + 0x7fffu + ((u >> 16) & 1u)) >> 16;
    return (unsigned short)r;
}
__device__ __forceinline__ float bf2f(unsigned short h) {
    return __builtin_bit_cast(float, (unsigned)h << 16);
}

// ---------------------------------------------------------------------------
// One-shot setup: weight bf16 conversion (blocks 0..1535), pe table
// (1536..1543), packed qkv bias (1544..1549).
__global__ void setup_all(const float* __restrict__ Wq, const float* __restrict__ Wk,
                          const float* __restrict__ Wv, const float* __restrict__ Wo,
                          const float* __restrict__ W1, const float* __restrict__ W2,
                          const float* __restrict__ bq, const float* __restrict__ bk,
                          const float* __restrict__ bv,
                          unsigned short* __restrict__ wB, float* __restrict__ pe,
                          float* __restrict__ bqkv) {
    int b = blockIdx.x, tid = threadIdx.x;
    if (b < 1536) {
        int i4 = b * 256 + tid;              // vec4 index over 2x786432 elems
        int e = i4 * 4;
        int l = (e >= 786432) ? 1 : 0;
        int r = e - l * 786432;
        const float* src;
        int off;
        if (r < 262144) {                    // Wq|Wk|Wv|Wo, 65536 each
            int w = r >> 16;
            off = (l << 16) + (r & 65535);
            src = (w == 0) ? Wq : (w == 1) ? Wk : (w == 2) ? Wv : Wo;
        } else if (r < 524288) {
            off = l * 262144 + (r - 262144);
            src = W1;
        } else {
            off = l * 262144 + (r - 524288);
            src = W2;
        }
        float4 v = *(const float4*)(src + off);
        unsigned short* o = wB + (size_t)l * 786432 + r;
        o[0] = f2bf(v.x); o[1] = f2bf(v.y); o[2] = f2bf(v.z); o[3] = f2bf(v.w);
    } else if (b < 1544) {
        int idx = (b - 1536) * 256 + tid;    // 0..2047
        int t = idx >> 8, c = idx & 255;
        int i2 = c & ~1;
        float div = __expf((float)i2 * (-logf(10000.f) / 256.f));
        float ang = (float)t * div;
        pe[idx] = (c & 1) ? cosf(ang) : sinf(ang);
    } else {
        int j = (b - 1544) * 256 + tid;      // 0..1535
        int l = j / 768, i = j - l * 768;
        float v = (i < 256) ? bq[l * 256 + i] : (i < 512) ? bk[l * 256 + i - 256]
                                                          : bv[l * 256 + i - 512];
        bqkv[j] = v;
    }
}

// ---------------------------------------------------------------------------
// x (B,T,C,H,W) -> hb (n, t, c) bf16, with += pe[t,c].
__global__ __launch_bounds__(256) void transpose_in(const float* __restrict__ x,
                                                    const float* __restrict__ pe,
                                                    unsigned short* __restrict__ hb) {
    int bty = blockIdx.x;
    int y = bty % 48; int bt = bty / 48; int t = bt & 7; int b = bt >> 3;
    int c0 = blockIdx.y * 32, w0 = blockIdx.z * 32;
    __shared__ float tile[32][33];
    int tid = threadIdx.x;
    const float* xp = x + ((size_t)(b * 8 + t) * 256) * 2304 + (size_t)y * 48;
    int wl = tid & 31, cl8 = tid >> 5;
#pragma unroll
    for (int it = 0; it < 4; ++it) {
        int c = c0 + it * 8 + cl8;
        int w = w0 + wl;
        if (w < 48) tile[it * 8 + cl8][wl] = xp[(size_t)c * 2304 + w] + pe[t * 256 + c];
    }
    __syncthreads();
    int cl = tid & 31, wl8 = tid >> 5;
#pragma unroll
    for (int it = 0; it < 4; ++it) {
        int w = w0 + it * 8 + wl8;
        int c = c0 + cl;
        if (w < 48) {
            size_t n = (size_t)(b * 48 + y) * 48 + w;
            hb[(n * 8 + t) * 256 + c] = f2bf(tile[cl][it * 8 + wl8]);
        }
    }
}

// out (B,C,H,W) fp32 = hb[n, T-1, c]
__global__ __launch_bounds__(256) void transpose_out(const unsigned short* __restrict__ hb,
                                                     float* __restrict__ out) {
    int by = blockIdx.x; int y = by % 48, b = by / 48;
    int c0 = blockIdx.y * 32, w0 = blockIdx.z * 32;
    __shared__ float tile[32][33];
    int tid = threadIdx.x;
    int cl = tid & 31, wl8 = tid >> 5;
#pragma unroll
    for (int it = 0; it < 4; ++it) {
        int w = w0 + it * 8 + wl8;
        if (w < 48) {
            size_t n = (size_t)(b * 48 + y) * 48 + w;
            tile[it * 8 + wl8][cl] = bf2f(hb[n * 2048 + 1792 + c0 + cl]);
        }
    }
    __syncthreads();
    int wl = tid & 31, cl8 = tid >> 5;
#pragma unroll
    for (int it = 0; it < 4; ++it) {
        int c = c0 + it * 8 + cl8;
        int w = w0 + wl;
        if (w < 48)
            out[((size_t)(b * 256 + c) * 48 + y) * 48 + w] = tile[wl][it * 8 + cl8];
    }
}

// ---------------------------------------------------------------------------
// bf16 MFMA GEMM (R16-proven structure): 128x128 tile, BK=32, 32 KB double-
// buffer -> 4 blocks/CU, counted vmcnt(4); swizzle slot ^= (row>>1)&3
// both-sides; setprio; XCD swizzle; LDS-restaged vectorized C store.
// ACT=1: fast tanh-GELU with v_rcp (no fp32 divide in the hot epilogue).
template <int ACT>
__global__ __launch_bounds__(256) void mgemm(const unsigned short* __restrict__ A,
                                             const unsigned short* __restrict__ W,
                                             const float* __restrict__ bias,
                                             unsigned short* __restrict__ C,
                                             int M, int N, int K) {
    __shared__ char smem[36864];          // loop: 32 KB dbuf; epi: [128][144] bf16
    const int tid = threadIdx.x;
    int nwg = gridDim.x * gridDim.y;
    int orig = blockIdx.y * gridDim.x + blockIdx.x;
    int wg = (orig & 7) * (nwg >> 3) + (orig >> 3);
    int bx = wg % gridDim.x, by = wg / gridDim.x;
    const int m0 = by * 128, n0 = bx * 128;
    const int lane = tid & 63, wv = tid >> 6;
    const int wr = wv >> 1, wc = wv & 1;
    const int lr = lane & 15, lk = lane >> 4;

    f32x4 acc[4][4] = {};

    // staging geometry; base pointers hoisted out of the K-loop
    int so[2];
    const unsigned short* pA[2];
    const unsigned short* pW[2];
#pragma unroll
    for (int it = 0; it < 2; ++it) {
        int o = it * 4096 + tid * 16;
        so[it] = o;
        int srow = o >> 6;                                 // row 0..127 (64-B rows)
        int sseg = ((o >> 4) & 3) ^ ((srow >> 1) & 3);     // pre-swizzled src slot
        pA[it] = A + (size_t)(m0 + srow) * K + sseg * 8;
        pW[it] = W + (size_t)(n0 + srow) * K + sseg * 8;
    }

    const int nt = K >> 5;
#pragma unroll
    for (int it = 0; it < 2; ++it)
        GLD_LDS16(pW[it], smem + 16384 + so[it]);
#pragma unroll
    for (int it = 0; it < 2; ++it)
        GLD_LDS16(pA[it], smem + so[it]);

    int cur = 0;
    for (int t = 0; t < nt; ++t) {
        char* Ac = smem + cur * 8192;
        char* Bc = smem + 16384 + cur * 8192;
        if (t + 1 < nt) {
            const int k1 = (t + 1) << 5;
            char* An = smem + (cur ^ 1) * 8192;
            char* Bn = smem + 16384 + (cur ^ 1) * 8192;
#pragma unroll
            for (int it = 0; it < 2; ++it)
                GLD_LDS16(pW[it] + k1, Bn + so[it]);
#pragma unroll
            for (int it = 0; it < 2; ++it)
                GLD_LDS16(pA[it] + k1, An + so[it]);
            asm volatile("s_waitcnt vmcnt(4)" ::: "memory");
        } else {
            asm volatile("s_waitcnt vmcnt(0)" ::: "memory");
        }
        __builtin_amdgcn_s_barrier();
        __builtin_amdgcn_s_setprio(1);
        {
            bf16x8 fA[4], fB[4];
#pragma unroll
            for (int f = 0; f < 4; ++f) {
                int row = wr * 64 + f * 16 + lr;
                fA[f] = *(const bf16x8*)(Ac + row * 64 + ((lk ^ ((row >> 1) & 3)) << 4));
                int col = wc * 64 + f * 16 + lr;
                fB[f] = *(const bf16x8*)(Bc + col * 64 + ((lk ^ ((col >> 1) & 3)) << 4));
            }
#pragma unroll
            for (int fi = 0; fi < 4; ++fi)
#pragma unroll
                for (int fj = 0; fj < 4; ++fj)
                    acc[fi][fj] = __builtin_amdgcn_mfma_f32_16x16x32_bf16(
                        fA[fi], fB[fj], acc[fi][fj], 0, 0, 0);
        }
        __builtin_amdgcn_s_setprio(0);
        __builtin_amdgcn_s_barrier();
        cur ^= 1;
    }

    unsigned short* S = (unsigned short*)smem;
#pragma unroll
    for (int fi = 0; fi < 4; ++fi) {
        int rl = wr * 64 + fi * 16 + lk * 4;
#pragma unroll
        for (int fj = 0; fj < 4; ++fj) {
            int cl = wc * 64 + fj * 16 + lr;
            float bv = bias[n0 + cl];
#pragma unroll
            for (int r = 0; r < 4; ++r) {
                float v = acc[fi][fj][r] + bv;
                if (ACT) {
                    // tanh-GELU via sigmoid, rcp instead of divide:
                    // v * 1/(1+exp(-2*0.79788456*(v+0.044715v^3)))
                    float u = 0.7978845608f * (v + 0.044715f * v * v * v);
                    v = v * __builtin_amdgcn_rcpf(1.0f + __expf(-2.0f * u));
                }
                S[(rl + r) * 144 + cl] = f2bf(v);
            }
        }
    }
    __syncthreads();
#pragma unroll
    for (int it = 0; it < 8; ++it) {
        int idx = it * 256 + tid;
        int row = idx >> 4, c8 = (idx & 15) * 8;
        bf16x8 v = *(const bf16x8*)&S[row * 144 + c8];
        *(bf16x8*)&C[(size_t)(m0 + row) * N + n0 + c8] = v;
    }
}

// ---------------------------------------------------------------------------
// Streaming residual + LayerNorm on the bf16 carrier:
//   z = hb + c (fp32 math);  hb = bf16( (z-mean)/sqrt(var+eps)*g + be )
__global__ __launch_bounds__(256) void resln(const unsigned short* __restrict__ c,
                                             unsigned short* __restrict__ hb,
                                             const float* __restrict__ g,
                                             const float* __restrict__ be) {
    int wv = threadIdx.x >> 6, lane = threadIdx.x & 63;
    size_t row = (size_t)blockIdx.x * 4 + wv;
    size_t off = row * 256 + lane * 4;
    bf16x4 hv = *(const bf16x4*)&hb[off];
    bf16x4 cv = *(const bf16x4*)&c[off];
    float4 z = {bf2f((unsigned short)hv[0]) + bf2f((unsigned short)cv[0]),
                bf2f((unsigned short)hv[1]) + bf2f((unsigned short)cv[1]),
                bf2f((unsigned short)hv[2]) + bf2f((unsigned short)cv[2]),
                bf2f((unsigned short)hv[3]) + bf2f((unsigned short)cv[3])};
    float s = z.x + z.y + z.z + z.w;
    float sq = z.x * z.x + z.y * z.y + z.z * z.z + z.w * z.w;
#pragma unroll
    for (int d = 1; d < 64; d <<= 1) {
        s += __shfl_xor(s, d);
        sq += __shfl_xor(sq, d);
    }
    float mean = s * (1.f / 256.f);
    float var = sq * (1.f / 256.f) - mean * mean;   // biased var
    float inv = 1.0f / sqrtf(var + 1e-5f);
    float4 gv = *(const float4*)&g[lane * 4];
    float4 bv = *(const float4*)&be[lane * 4];
    bf16x4 ob;
    ob[0] = (short)f2bf((z.x - mean) * inv * gv.x + bv.x);
    ob[1] = (short)f2bf((z.y - mean) * inv * gv.y + bv.y);
    ob[2] = (short)f2bf((z.z - mean) * inv * gv.z + bv.z);
    ob[3] = (short)f2bf((z.w - mean) * inv * gv.w + bv.w);
    *(bf16x4*)&hb[off] = ob;
}

// ---------------------------------------------------------------------------
// Causal MHSA: qkv packed bf16 [row][768] (q|k|v), ctx out bf16 [row][256].
__global__ __launch_bounds__(256) void attn_kernel(const unsigned short* __restrict__ qkv,
                                                   unsigned short* __restrict__ ctx) {
    __shared__ float Qs[8 * 260], Ks[8 * 260], Vs[8 * 260];
    int n = blockIdx.x;
    int tid = threadIdx.x;
    size_t base = (size_t)n * 6144;             // 8*768
#pragma unroll
    for (int it = 0; it < 6; ++it) {
        int i4 = it * 256 + tid;                // 0..1535
        int t = i4 / 192;
        int c4 = (i4 - t * 192) * 4;            // 0..764, mult of 4
        const unsigned short* p = qkv + base + (size_t)t * 768 + c4;
        float4 f = {bf2f(p[0]), bf2f(p[1]), bf2f(p[2]), bf2f(p[3])};
        float* dst = (c4 < 256) ? &Qs[t * 260 + c4]
                   : (c4 < 512) ? &Ks[t * 260 + (c4 - 256)]
                                : &Vs[t * 260 + (c4 - 512)];
        *(float4*)dst = f;
    }
    __syncthreads();
    int wid = tid >> 6, lane = tid & 63;
    int t = lane >> 3, s = lane & 7;
    size_t obase = (size_t)n * 2048;
    for (int hh = wid; hh < 8; hh += 4) {
        float acc = 0.f;
        int qb = t * 260 + hh * 32, kb = s * 260 + hh * 32;
#pragma unroll
        for (int jj = 0; jj < 8; ++jj) {
            float4 qv = *(const float4*)&Qs[qb + jj * 4];
            float4 kv = *(const float4*)&Ks[kb + jj * 4];
            acc += qv.x * kv.x + qv.y * kv.y + qv.z * kv.z + qv.w * kv.w;
        }
        acc *= 0.17677669529663687f;            // 1/sqrt(32)
        if (s > t) acc = -1e30f;
        float m = acc;
        m = fmaxf(m, __shfl_xor(m, 1));
        m = fmaxf(m, __shfl_xor(m, 2));
        m = fmaxf(m, __shfl_xor(m, 4));
        float e = __expf(acc - m);
        float sum = e;
        sum += __shfl_xor(sum, 1);
        sum += __shfl_xor(sum, 2);
        sum += __shfl_xor(sum, 4);
        float p = e / sum;
        float a4[4] = {0.f, 0.f, 0.f, 0.f};
#pragma unroll
        for (int s2 = 0; s2 < 8; ++s2) {
            float ps = __shfl(p, (lane & ~7) | s2);
            int vb = s2 * 260 + hh * 32 + s;
#pragma unroll
            for (int r = 0; r < 4; ++r) a4[r] += ps * Vs[vb + 8 * r];
        }
#pragma unroll
        for (int r = 0; r < 4; ++r)
            ctx[obase + t * 256 + hh * 32 + s + 8 * r] = f2bf(a4[r]);
    }
}

// ---------------------------------------------------------------------------
extern "C" void kernel_launch(void* const* d_in, const int* in_sizes, int n_in,
                              void* d_out, int out_size, void* d_ws, size_t ws_size,
                              hipStream_t stream) {
    const float* x   = (const float*)d_in[0];
    const float* Wq  = (const float*)d_in[1];
    const float* bq  = (const float*)d_in[2];
    const float* Wk  = (const float*)d_in[3];
    const float* bk  = (const float*)d_in[4];
    const float* Wv  = (const float*)d_in[5];
    const float* bv  = (const float*)d_in[6];
    const float* Wo  = (const float*)d_in[7];
    const float* bo  = (const float*)d_in[8];
    const float* g1  = (const float*)d_in[9];
    const float* be1 = (const float*)d_in[10];
    const float* W1  = (const float*)d_in[11];
    const float* b1  = (const float*)d_in[12];
    const float* W2  = (const float*)d_in[13];
    const float* b2  = (const float*)d_in[14];
    const float* g2  = (const float*)d_in[15];
    const float* be2 = (const float*)d_in[16];

    // ---- workspace layout (bytes); end = 229,662,720 < proven 264.3 MB ----
    char* base = (char*)d_ws;
    const size_t O_PE = 0;                           // 16 KB reserved
    const size_t O_W  = 16384;                       // bf16 weights: 3,145,728
    const size_t O_BQ = O_W + 3145728;               // packed qkv bias (8 KB)
    const size_t O_HB = O_BQ + 8192;                 // hb bf16: 37,748,736
    const size_t O_P1 = O_HB + (size_t)TOK * 512;    // qkv/wo-out/f1o pool
    const size_t O_CT = O_P1 + (size_t)TOK * 2048;   // ctx / f2-out

    float*          pe   = (float*)(base + O_PE);
    unsigned short* wB   = (unsigned short*)(base + O_W);
    float*          bqkv = (float*)(base + O_BQ);
    unsigned short* hb   = (unsigned short*)(base + O_HB);
    unsigned short* p1   = (unsigned short*)(base + O_P1);
    unsigned short* ctxb = (unsigned short*)(base + O_CT);

    setup_all<<<1550, 256, 0, stream>>>(Wq, Wk, Wv, Wo, W1, W2, bq, bk, bv,
                                        wB, pe, bqkv);
    transpose_in<<<dim3(1536, 8, 2), 256, 0, stream>>>(x, pe, hb);

    const int gy = TOK / 128;                        // 576
    for (int l = 0; l < 2; ++l) {
        unsigned short* wqkv = wB + (size_t)l * 786432;
        unsigned short* wo   = wqkv + 196608;
        unsigned short* w1   = wqkv + 262144;
        unsigned short* w2   = wqkv + 524288;

        // fused qkv projection (N=768) -> p1
        mgemm<0><<<dim3(6, gy), 256, 0, stream>>>(hb, wqkv, bqkv + l * 768, p1, TOK, 768, 256);
        attn_kernel<<<SEQ, 256, 0, stream>>>(p1, ctxb);
        // Wo projection: reads ctx, writes wo-out into p1 (qkv dead)
        mgemm<0><<<dim3(2, gy), 256, 0, stream>>>(ctxb, wo, bo + l * 256, p1, TOK, 256, 256);
        resln<<<TOK / 4, 256, 0, stream>>>(p1, hb, g1 + l * 256, be1 + l * 256);
        // FFN up + GELU -> p1 (wo-out dead)
        mgemm<1><<<dim3(8, gy), 256, 0, stream>>>(hb, w1, b1 + l * 1024, p1, TOK, 1024, 256);
        // FFN down -> ctx slot (dead since wo)
        mgemm<0><<<dim3(2, gy), 256, 0, stream>>>(p1, w2, b2 + l * 256, ctxb, TOK, 256, 1024);
        resln<<<TOK / 4, 256, 0, stream>>>(ctxb, hb, g2 + l * 256, be2 + l * 256);
    }

    transpose_out<<<dim3(192, 8, 2), 256, 0, stream>>>(hb, (float*)d_out);
}